// Round 3
// baseline (247.315 us; speedup 1.0000x reference)
//
#include <hip/hip_runtime.h>

#define DIN 256
#define DH  128
#define DOUT 64
#define BSH  7          // bucket = 128 nodes
#define BNODES 128
#define MAXBUK 400      // >= ceil(N/128); N=50000 -> 391
#define NBLK 512        // histogram/scatter grid

typedef unsigned int  u32;
typedef unsigned short u16;
typedef __attribute__((ext_vector_type(8))) short bf16x8;
typedef __attribute__((ext_vector_type(4))) float f32x4;

__device__ inline u16 f2bf(float f) {            // fp32 -> bf16 round-nearest-even
  u32 u = __float_as_uint(f);
  u32 r = u + 0x7FFF + ((u >> 16) & 1);
  return (u16)(r >> 16);
}
__device__ inline float bf2f_lo(u32 packed) { return __uint_as_float(packed << 16); }
__device__ inline float bf2f_hi(u32 packed) { return __uint_as_float(packed & 0xFFFF0000u); }

// ---------- radix-style CSR construction (no global atomics) ----------

__global__ __launch_bounds__(256) void hist_kernel(const int* __restrict__ dst,
    int* __restrict__ counts, int E, int nbuk) {
  __shared__ int h[MAXBUK];
  int tid = threadIdx.x, b = blockIdx.x;
  for (int i = tid; i < nbuk; i += 256) h[i] = 0;
  __syncthreads();
  int ech = (E + NBLK - 1) / NBLK;
  int e0 = b * ech, e1 = min(E, e0 + ech);
  for (int e = e0 + tid; e < e1; e += 256)
    atomicAdd(&h[dst[e] >> BSH], 1);
  __syncthreads();
  for (int i = tid; i < nbuk; i += 256) counts[(size_t)i * NBLK + b] = h[i];
}

__global__ __launch_bounds__(256) void col_scan(int* __restrict__ counts,
    int* __restrict__ colsum, int nbuk) {
  __shared__ int sm[256];
  __shared__ int carry;
  int buk = blockIdx.x, t = threadIdx.x;
  if (t == 0) carry = 0;
  __syncthreads();
  int* row = counts + (size_t)buk * NBLK;
  for (int base = 0; base < NBLK; base += 256) {
    int v = row[base + t];
    sm[t] = v;
    __syncthreads();
    for (int d = 1; d < 256; d <<= 1) {
      int a = (t >= d) ? sm[t - d] : 0;
      __syncthreads();
      sm[t] += a;
      __syncthreads();
    }
    int excl = sm[t] - v + carry;
    row[base + t] = excl;
    __syncthreads();
    if (t == 255) carry = excl + v;
    __syncthreads();
  }
  if (t == 0) colsum[buk] = carry;
}

__global__ __launch_bounds__(256) void scan_block(int* partial, int* total_out, int nb, int n) {
  __shared__ int sm[256];
  __shared__ int carry;
  int t = threadIdx.x;
  if (t == 0) carry = 0;
  __syncthreads();
  for (int base = 0; base < nb; base += 256) {
    int g = base + t;
    int v = (g < nb) ? partial[g] : 0;
    sm[t] = v;
    __syncthreads();
    for (int d = 1; d < 256; d <<= 1) {
      int add = (t >= d) ? sm[t - d] : 0;
      __syncthreads();
      sm[t] += add;
      __syncthreads();
    }
    int excl = sm[t] - v + carry;
    if (g < nb) partial[g] = excl;
    __syncthreads();
    if (t == 255) carry = excl + v;
    __syncthreads();
  }
  if (t == 0) total_out[n] = carry;
}

__global__ __launch_bounds__(256) void scatter_kernel(const int* __restrict__ src,
    const int* __restrict__ dst, const int* __restrict__ counts,
    const int* __restrict__ bb, u32* __restrict__ ebuf, int E, int nbuk) {
  __shared__ int cur[MAXBUK];
  int tid = threadIdx.x, b = blockIdx.x;
  for (int i = tid; i < nbuk; i += 256)
    cur[i] = bb[i] + counts[(size_t)i * NBLK + b];
  __syncthreads();
  int ech = (E + NBLK - 1) / NBLK;
  int e0 = b * ech, e1 = min(E, e0 + ech);
  for (int e = e0 + tid; e < e1; e += 256) {
    int d = dst[e];
    int r = atomicAdd(&cur[d >> BSH], 1);
    ebuf[r] = (u32)src[e] | ((u32)(d & (BNODES - 1)) << 16);   // N < 65536
  }
}

__global__ __launch_bounds__(256) void bucket_node_count(const u32* __restrict__ ebuf,
    const int* __restrict__ bb, int* __restrict__ cnt, int N) {
  __shared__ int c[BNODES];
  int b = blockIdx.x, tid = threadIdx.x;
  if (tid < BNODES) c[tid] = 0;
  __syncthreads();
  int e0 = bb[b], e1 = bb[b + 1];
  for (int e = e0 + tid; e < e1; e += 256)
    atomicAdd(&c[ebuf[e] >> 16], 1);
  __syncthreads();
  int node = b * BNODES + tid;
  if (tid < BNODES && node < N) cnt[node] = c[tid];
}

__global__ __launch_bounds__(256) void reduce_chunks(const int* __restrict__ cnt,
                                                     int* __restrict__ partial, int n) {
  int t = threadIdx.x;
  int g = blockIdx.x * 256 + t;
  int v = (g < n) ? cnt[g] : 0;
  #pragma unroll
  for (int o = 32; o > 0; o >>= 1) v += __shfl_down(v, o, 64);
  __shared__ int sm[4];
  if ((t & 63) == 0) sm[t >> 6] = v;
  __syncthreads();
  if (t == 0) partial[blockIdx.x] = sm[0] + sm[1] + sm[2] + sm[3];
}

__global__ __launch_bounds__(256) void scan_chunks(const int* __restrict__ cnt,
    const int* __restrict__ chunkoff, int* __restrict__ rowptr,
    float* __restrict__ dinv, int n) {
  __shared__ int sm[256];
  int t = threadIdx.x, g = blockIdx.x * 256 + t;
  int v = (g < n) ? cnt[g] : 0;
  sm[t] = v;
  __syncthreads();
  for (int d = 1; d < 256; d <<= 1) {
    int add = (t >= d) ? sm[t - d] : 0;
    __syncthreads();
    sm[t] += add;
    __syncthreads();
  }
  if (g < n) {
    rowptr[g] = sm[t] - v + chunkoff[blockIdx.x];
    dinv[g] = rsqrtf((float)(v + 1));       // +1 self-loop
  }
}

__global__ __launch_bounds__(256) void bucket_fill(const u32* __restrict__ ebuf,
    const int* __restrict__ bb, const int* __restrict__ rowptr, int* __restrict__ csr) {
  __shared__ int c[BNODES];
  int b = blockIdx.x, tid = threadIdx.x;
  if (tid < BNODES) c[tid] = 0;
  __syncthreads();
  int e0 = bb[b], e1 = bb[b + 1];
  for (int e = e0 + tid; e < e1; e += 256) {
    u32 p = ebuf[e];
    int nl = p >> 16;
    int r = atomicAdd(&c[nl], 1);
    csr[rowptr[b * BNODES + nl] + r] = (int)(p & 0xFFFFu);
  }
}

// ---------- W1,W2 -> bf16 transposed (one-shot, tiny) ----------

__global__ __launch_bounds__(256) void w_prep(const float* __restrict__ W1,
    const float* __restrict__ W2, u16* __restrict__ w1t, u16* __restrict__ w2t) {
  int t = blockIdx.x * 256 + threadIdx.x;     // 40960 threads
  if (t < DH * DIN) {
    int n = t >> 8, k = t & 255;
    w1t[t] = f2bf(W1[k * DH + n]);            // w1t[n*256+k]
  } else {
    int t2 = t - DH * DIN;
    int n = t2 >> 7, k = t2 & 127;
    w2t[t2] = f2bf(W2[k * DOUT + n]);         // w2t[n*128+k]
  }
}

// ---------- GEMM1: bf16 MFMA, BM=64 BN=128 BK=64, epilogue dinv*bf16 ----------

__global__ __launch_bounds__(256) void gemm1_mfma(const float* __restrict__ x,
    const u16* __restrict__ w1t, const float* __restrict__ dinv,
    u16* __restrict__ h1, int M) {
  __shared__ u16 As[64][72];
  __shared__ u16 Bs[128][72];
  const int tid = threadIdx.x;
  const int lane = tid & 63, w = tid >> 6;
  const int row16 = lane & 15, quad = lane >> 4;
  const int rowBase = blockIdx.x * 64;
  f32x4 acc[8];
  #pragma unroll
  for (int nt = 0; nt < 8; ++nt) acc[nt] = (f32x4)(0.f);

  for (int kt = 0; kt < DIN; kt += 64) {
    {
      int r = tid >> 2, kq = tid & 3;
      int grow = rowBase + r;
      #pragma unroll
      for (int i = 0; i < 4; ++i) {
        float4 v = make_float4(0.f, 0.f, 0.f, 0.f);
        if (grow < M) v = *(const float4*)&x[(size_t)grow * DIN + kt + kq * 16 + i * 4];
        u32 lo = (u32)f2bf(v.x) | ((u32)f2bf(v.y) << 16);
        u32 hi = (u32)f2bf(v.z) | ((u32)f2bf(v.w) << 16);
        *(uint2*)&As[r][kq * 16 + i * 4] = make_uint2(lo, hi);
      }
    }
    {
      int n = tid >> 1, half = tid & 1;
      const uint4* s = (const uint4*)&w1t[n * DIN + kt + half * 32];
      uint4* d = (uint4*)&Bs[n][half * 32];
      d[0] = s[0]; d[1] = s[1]; d[2] = s[2]; d[3] = s[3];
    }
    __syncthreads();
    #pragma unroll
    for (int ks = 0; ks < 64; ks += 32) {
      bf16x8 a = *(bf16x8*)&As[w * 16 + row16][ks + quad * 8];
      #pragma unroll
      for (int nt = 0; nt < 8; ++nt) {
        bf16x8 b = *(bf16x8*)&Bs[nt * 16 + row16][ks + quad * 8];
        acc[nt] = __builtin_amdgcn_mfma_f32_16x16x32_bf16(a, b, acc[nt], 0, 0, 0);
      }
    }
    __syncthreads();
  }
  #pragma unroll
  for (int reg = 0; reg < 4; ++reg) {
    int row = rowBase + w * 16 + quad * 4 + reg;
    if (row < M) {
      float s = dinv[row];
      #pragma unroll
      for (int nt = 0; nt < 8; ++nt)
        h1[(size_t)row * DH + nt * 16 + row16] = f2bf(acc[nt][reg] * s);
    }
  }
}

// ---------- GEMM2: bf16 MFMA, BM=64 BN=64, K=128 staged once ----------

__global__ __launch_bounds__(256) void gemm2_mfma(const u16* __restrict__ g1,
    const u16* __restrict__ w2t, const float* __restrict__ dinv,
    u16* __restrict__ h2, int M) {
  __shared__ u16 As[64][136];
  __shared__ u16 Bs[64][136];
  const int tid = threadIdx.x;
  const int lane = tid & 63, w = tid >> 6;
  const int row16 = lane & 15, quad = lane >> 4;
  const int rowBase = blockIdx.x * 64;
  f32x4 acc[4];
  #pragma unroll
  for (int nt = 0; nt < 4; ++nt) acc[nt] = (f32x4)(0.f);

  #pragma unroll
  for (int i = 0; i < 4; ++i) {        // A: 64 rows x 128 bf16 (1024 uint4)
    int flat = i * 256 + tid;
    int r = flat >> 4, c = flat & 15;
    int grow = rowBase + r;
    uint4 v = make_uint4(0, 0, 0, 0);
    if (grow < M) v = *(const uint4*)&g1[(size_t)grow * DH + c * 8];
    *(uint4*)&As[r][c * 8] = v;
  }
  #pragma unroll
  for (int i = 0; i < 4; ++i) {        // B: w2t 64 x 128 bf16
    int flat = i * 256 + tid;
    int r = flat >> 4, c = flat & 15;
    *(uint4*)&Bs[r][c * 8] = *(const uint4*)&w2t[r * DH + c * 8];
  }
  __syncthreads();
  #pragma unroll
  for (int ks = 0; ks < 128; ks += 32) {
    bf16x8 a = *(bf16x8*)&As[w * 16 + row16][ks + quad * 8];
    #pragma unroll
    for (int nt = 0; nt < 4; ++nt) {
      bf16x8 b = *(bf16x8*)&Bs[nt * 16 + row16][ks + quad * 8];
      acc[nt] = __builtin_amdgcn_mfma_f32_16x16x32_bf16(a, b, acc[nt], 0, 0, 0);
    }
  }
  #pragma unroll
  for (int reg = 0; reg < 4; ++reg) {
    int row = rowBase + w * 16 + quad * 4 + reg;
    if (row < M) {
      float s = dinv[row];
      #pragma unroll
      for (int nt = 0; nt < 4; ++nt)
        h2[(size_t)row * DOUT + nt * 16 + row16] = f2bf(acc[nt][reg] * s);
    }
  }
}

// ---------- pull aggregation ----------
// Latency-bound (Little's law): the lever is bytes-in-flight per wave.
// aggregate1: 8 dwordx4 gathers in flight (32-edge main step) + csr prefetch.
// aggregate2: 2 nodes per wave (one per 32-lane half), 8 gathers in flight.

// layer 1: rows 256 B (128 bf16). One node/wave, 4 edge-groups x 16 lanes.
__global__ __launch_bounds__(256) void aggregate1(const u16* __restrict__ h,
    const int* __restrict__ rowptr, const int* __restrict__ csr,
    const float* __restrict__ dinv, const float* __restrict__ bias,
    u16* __restrict__ out, int n) {
  const int lane = threadIdx.x & 63;
  const int sub = lane >> 4;          // edge slot within quartet (0..3)
  const int l16 = lane & 15;          // 16B chunk within 256B row
  int node = blockIdx.x * 4 + (threadIdx.x >> 6);
  if (node >= n) return;
  node = __builtin_amdgcn_readfirstlane(node);
  const float di = dinv[node];
  const size_t coff = (size_t)l16 * 8;

  float a[8];
  {   // self-loop row (only sub==0 keeps it)
    uint4 v = *(const uint4*)&h[(size_t)node * DH + coff];
    float ms = (sub == 0) ? 1.f : 0.f;
    a[0] = ms * bf2f_lo(v.x); a[1] = ms * bf2f_hi(v.x);
    a[2] = ms * bf2f_lo(v.y); a[3] = ms * bf2f_hi(v.y);
    a[4] = ms * bf2f_lo(v.z); a[5] = ms * bf2f_hi(v.z);
    a[6] = ms * bf2f_lo(v.w); a[7] = ms * bf2f_hi(v.w);
  }

  int p = rowptr[node];
  const int pe = rowptr[node + 1];
  int g = p + lane;
  int si = (g < pe) ? csr[g] : 0;            // 64 indices, one instruction
  while (p < pe) {
    int rem = pe - p; if (rem > 64) rem = 64;
    int gn = p + 64 + lane;                  // prefetch next chunk's indices
    int si_next = (gn < pe) ? csr[gn] : 0;
    int t = 0;
    for (; t + 32 <= rem; t += 32) {         // 8 gathers in flight (typical node: 1 pass)
      uint4 v[8];
      #pragma unroll
      for (int q = 0; q < 8; ++q) {
        int idx = __shfl(si, t + q * 4 + sub, 64);
        v[q] = *(const uint4*)&h[(size_t)idx * DH + coff];
      }
      #pragma unroll
      for (int q = 0; q < 8; ++q) {
        a[0] += bf2f_lo(v[q].x); a[1] += bf2f_hi(v[q].x);
        a[2] += bf2f_lo(v[q].y); a[3] += bf2f_hi(v[q].y);
        a[4] += bf2f_lo(v[q].z); a[5] += bf2f_hi(v[q].z);
        a[6] += bf2f_lo(v[q].w); a[7] += bf2f_hi(v[q].w);
      }
    }
    for (; t < rem; t += 16) {               // masked 16-step tail
      uint4 v[4]; float m[4];
      #pragma unroll
      for (int q = 0; q < 4; ++q) {
        int e = t + q * 4 + sub;
        int idx = __shfl(si, e, 64);         // e <= 63
        v[q] = *(const uint4*)&h[(size_t)idx * DH + coff];
        m[q] = (e < rem) ? 1.f : 0.f;
      }
      #pragma unroll
      for (int q = 0; q < 4; ++q) {
        a[0] = fmaf(m[q], bf2f_lo(v[q].x), a[0]); a[1] = fmaf(m[q], bf2f_hi(v[q].x), a[1]);
        a[2] = fmaf(m[q], bf2f_lo(v[q].y), a[2]); a[3] = fmaf(m[q], bf2f_hi(v[q].y), a[3]);
        a[4] = fmaf(m[q], bf2f_lo(v[q].z), a[4]); a[5] = fmaf(m[q], bf2f_hi(v[q].z), a[5]);
        a[6] = fmaf(m[q], bf2f_lo(v[q].w), a[6]); a[7] = fmaf(m[q], bf2f_hi(v[q].w), a[7]);
      }
    }
    p += 64;
    si = si_next;
  }

  #pragma unroll
  for (int i = 0; i < 8; ++i) {              // reduce across the 4 edge-groups
    a[i] += __shfl_xor(a[i], 16, 64);
    a[i] += __shfl_xor(a[i], 32, 64);
  }

  if (sub == 0) {                            // lanes 0..15 hold the full row
    const int c0 = l16 * 8;
    float4 b0 = *(const float4*)&bias[c0];
    float4 b1 = *(const float4*)&bias[c0 + 4];
    float r0 = fmaxf(fmaf(a[0], di, b0.x), 0.f);
    float r1 = fmaxf(fmaf(a[1], di, b0.y), 0.f);
    float r2 = fmaxf(fmaf(a[2], di, b0.z), 0.f);
    float r3 = fmaxf(fmaf(a[3], di, b0.w), 0.f);
    float r4 = fmaxf(fmaf(a[4], di, b1.x), 0.f);
    float r5 = fmaxf(fmaf(a[5], di, b1.y), 0.f);
    float r6 = fmaxf(fmaf(a[6], di, b1.z), 0.f);
    float r7 = fmaxf(fmaf(a[7], di, b1.w), 0.f);
    u32 pk[4];
    pk[0] = (u32)f2bf(r0) | ((u32)f2bf(r1) << 16);
    pk[1] = (u32)f2bf(r2) | ((u32)f2bf(r3) << 16);
    pk[2] = (u32)f2bf(r4) | ((u32)f2bf(r5) << 16);
    pk[3] = (u32)f2bf(r6) | ((u32)f2bf(r7) << 16);
    *(uint4*)&out[(size_t)node * DH + c0] = *(uint4*)pk;
  }
}

// layer 2: rows 128 B (64 bf16). TWO nodes per wave (one per 32-lane half),
// 4 edge-groups x 8 lanes per half, 8 gathers in flight. fp32 output.
__global__ __launch_bounds__(256) void aggregate2(const u16* __restrict__ h,
    const int* __restrict__ rowptr, const int* __restrict__ csr,
    const float* __restrict__ dinv, const float* __restrict__ bias,
    float* __restrict__ out, int n) {
  const int lane = threadIdx.x & 63;
  const int halfbase = lane & 32;     // 0 or 32: which half-wave (which node)
  const int sub = (lane >> 3) & 3;    // edge slot within quad (0..3)
  const int l8 = lane & 7;            // 16B chunk within 128B row
  const int node = blockIdx.x * 8 + ((threadIdx.x >> 6) << 1) + (halfbase >> 5);
  if (node >= n) return;
  const float di = dinv[node];
  const size_t coff = (size_t)l8 * 8;

  float a[8];
  {
    uint4 v = *(const uint4*)&h[(size_t)node * DOUT + coff];
    float ms = (sub == 0) ? 1.f : 0.f;
    a[0] = ms * bf2f_lo(v.x); a[1] = ms * bf2f_hi(v.x);
    a[2] = ms * bf2f_lo(v.y); a[3] = ms * bf2f_hi(v.y);
    a[4] = ms * bf2f_lo(v.z); a[5] = ms * bf2f_hi(v.z);
    a[6] = ms * bf2f_lo(v.w); a[7] = ms * bf2f_hi(v.w);
  }

  int p = rowptr[node];
  const int pe = rowptr[node + 1];
  int g = p + (lane & 31);
  int si = (g < pe) ? csr[g] : 0;            // 32 indices per half
  while (p < pe) {
    int rem = pe - p; if (rem > 32) rem = 32;
    int gn = p + 32 + (lane & 31);           // prefetch next chunk
    int si_next = (gn < pe) ? csr[gn] : 0;
    int t = 0;
    for (; t + 32 <= rem; t += 32) {         // 8 gathers in flight (typical: 1 pass)
      uint4 v[8];
      #pragma unroll
      for (int q = 0; q < 8; ++q) {
        int idx = __shfl(si, halfbase | (q * 4 + sub), 64);
        v[q] = *(const uint4*)&h[(size_t)idx * DOUT + coff];
      }
      #pragma unroll
      for (int q = 0; q < 8; ++q) {
        a[0] += bf2f_lo(v[q].x); a[1] += bf2f_hi(v[q].x);
        a[2] += bf2f_lo(v[q].y); a[3] += bf2f_hi(v[q].y);
        a[4] += bf2f_lo(v[q].z); a[5] += bf2f_hi(v[q].z);
        a[6] += bf2f_lo(v[q].w); a[7] += bf2f_hi(v[q].w);
      }
    }
    for (; t < rem; t += 16) {               // masked 16-step tail
      uint4 v[4]; float m[4];
      #pragma unroll
      for (int q = 0; q < 4; ++q) {
        int e = t + q * 4 + sub;             // e <= 31
        int idx = __shfl(si, halfbase | e, 64);
        v[q] = *(const uint4*)&h[(size_t)idx * DOUT + coff];
        m[q] = (e < rem) ? 1.f : 0.f;
      }
      #pragma unroll
      for (int q = 0; q < 4; ++q) {
        a[0] = fmaf(m[q], bf2f_lo(v[q].x), a[0]); a[1] = fmaf(m[q], bf2f_hi(v[q].x), a[1]);
        a[2] = fmaf(m[q], bf2f_lo(v[q].y), a[2]); a[3] = fmaf(m[q], bf2f_hi(v[q].y), a[3]);
        a[4] = fmaf(m[q], bf2f_lo(v[q].z), a[4]); a[5] = fmaf(m[q], bf2f_hi(v[q].z), a[5]);
        a[6] = fmaf(m[q], bf2f_lo(v[q].w), a[6]); a[7] = fmaf(m[q], bf2f_hi(v[q].w), a[7]);
      }
    }
    p += 32;
    si = si_next;
  }

  #pragma unroll
  for (int i = 0; i < 8; ++i) {              // reduce across 4 edge-groups (within half)
    a[i] += __shfl_xor(a[i], 8, 64);
    a[i] += __shfl_xor(a[i], 16, 64);
  }

  if (sub == 0) {                            // lanes 0..7 / 32..39 hold full rows
    const int c0 = l8 * 8;
    float4 b0 = *(const float4*)&bias[c0];
    float4 b1 = *(const float4*)&bias[c0 + 4];
    float4 r0, r1;
    r0.x = fmaf(a[0], di, b0.x);
    r0.y = fmaf(a[1], di, b0.y);
    r0.z = fmaf(a[2], di, b0.z);
    r0.w = fmaf(a[3], di, b0.w);
    r1.x = fmaf(a[4], di, b1.x);
    r1.y = fmaf(a[5], di, b1.y);
    r1.z = fmaf(a[6], di, b1.z);
    r1.w = fmaf(a[7], di, b1.w);
    *(float4*)&out[(size_t)node * DOUT + c0] = r0;
    *(float4*)&out[(size_t)node * DOUT + c0 + 4] = r1;
  }
}

// ---------- launch ----------

extern "C" void kernel_launch(void* const* d_in, const int* in_sizes, int n_in,
                              void* d_out, int out_size, void* d_ws, size_t ws_size,
                              hipStream_t stream) {
  const float* x  = (const float*)d_in[0];
  const int*   ei = (const int*)d_in[1];
  const float* W1 = (const float*)d_in[2];
  const float* b1 = (const float*)d_in[3];
  const float* W2 = (const float*)d_in[4];
  const float* b2 = (const float*)d_in[5];
  float* out = (float*)d_out;

  const int N = in_sizes[0] / DIN;   // 50000
  const int E = in_sizes[1] / 2;     // 1600000
  const int* src = ei;
  const int* dst = ei + E;
  const int NB = (N + 255) / 256;
  const int nbuk = (N + BNODES - 1) / BNODES;   // 391 (<= MAXBUK)

  char* ws = (char*)d_ws;
  size_t o = 0;
  auto alloc = [&](size_t bytes) { size_t r = o; o += (bytes + 511) & ~(size_t)511; return r; };
  size_t colsum_o  = alloc((size_t)(nbuk + 1) * 4);
  size_t counts_o  = alloc((size_t)nbuk * NBLK * 4);
  size_t rowptr_o  = alloc((size_t)(N + 1) * 4);
  size_t partial_o = alloc((size_t)NB * 4);
  size_t dinv_o    = alloc((size_t)N * 4);
  size_t cnt_o     = alloc((size_t)N * 4);
  size_t w1t_o     = alloc((size_t)DH * DIN * 2);
  size_t w2t_o     = alloc((size_t)DOUT * DH * 2);
  size_t csr_o     = alloc((size_t)E * 4);
  size_t h1_o      = alloc((size_t)N * DH * 2);   // bf16
  size_t g1_o      = alloc((size_t)N * DH * 2);   // bf16 (GEMM2 input)
  size_t h2_o      = h1_o;   // h1 dead after aggregate1 -> reuse (bf16)
  size_t ebuf_o    = g1_o;   // ebuf dead before aggregate1 writes g1

  int*   colsum  = (int*)(ws + colsum_o);   // becomes bb after scan_block
  int*   counts  = (int*)(ws + counts_o);
  int*   rowptr  = (int*)(ws + rowptr_o);
  int*   partial = (int*)(ws + partial_o);
  float* dinv    = (float*)(ws + dinv_o);
  int*   cnt     = (int*)(ws + cnt_o);
  u16*   w1t     = (u16*)(ws + w1t_o);
  u16*   w2t     = (u16*)(ws + w2t_o);
  int*   csr     = (int*)(ws + csr_o);
  u16*   h1      = (u16*)(ws + h1_o);
  u16*   g1      = (u16*)(ws + g1_o);
  u16*   h2      = (u16*)(ws + h2_o);
  u32*   ebuf    = (u32*)(ws + ebuf_o);

  w_prep<<<(DH * DIN + DOUT * DH) / 256, 256, 0, stream>>>(W1, W2, w1t, w2t);
  hist_kernel<<<NBLK, 256, 0, stream>>>(dst, counts, E, nbuk);
  col_scan<<<nbuk, 256, 0, stream>>>(counts, colsum, nbuk);
  scan_block<<<1, 256, 0, stream>>>(colsum, colsum, nbuk, nbuk);  // colsum -> bb, bb[nbuk]=E
  scatter_kernel<<<NBLK, 256, 0, stream>>>(src, dst, counts, colsum, ebuf, E, nbuk);
  bucket_node_count<<<nbuk, 256, 0, stream>>>(ebuf, colsum, cnt, N);
  reduce_chunks<<<NB, 256, 0, stream>>>(cnt, partial, N);
  scan_block<<<1, 256, 0, stream>>>(partial, rowptr, NB, N);
  scan_chunks<<<NB, 256, 0, stream>>>(cnt, partial, rowptr, dinv, N);
  bucket_fill<<<nbuk, 256, 0, stream>>>(ebuf, colsum, rowptr, csr);

  gemm1_mfma<<<(N + 63) / 64, 256, 0, stream>>>(x, w1t, dinv, h1, N);
  aggregate1<<<(N + 3) / 4, 256, 0, stream>>>(h1, rowptr, csr, dinv, b1, g1, N);
  gemm2_mfma<<<(N + 63) / 64, 256, 0, stream>>>(g1, w2t, dinv, h2, N);
  aggregate2<<<(N + 7) / 8, 256, 0, stream>>>(h2, rowptr, csr, dinv, b2, out, N);
}

// Round 4
// 241.683 us; speedup vs baseline: 1.0233x; 1.0233x over previous
//
#include <hip/hip_runtime.h>

#define DIN 256
#define DH  128
#define DOUT 64
#define BSH  7          // bucket = 128 nodes
#define BNODES 128
#define MAXBUK 400      // >= ceil(N/128); N=50000 -> 391
#define NBLK 512        // histogram/scatter grid

typedef unsigned int  u32;
typedef unsigned short u16;
typedef __attribute__((ext_vector_type(8))) short bf16x8;
typedef __attribute__((ext_vector_type(4))) float f32x4;

__device__ inline u16 f2bf(float f) {            // fp32 -> bf16 round-nearest-even
  u32 u = __float_as_uint(f);
  u32 r = u + 0x7FFF + ((u >> 16) & 1);
  return (u16)(r >> 16);
}
__device__ inline float bf2f_lo(u32 packed) { return __uint_as_float(packed << 16); }
__device__ inline float bf2f_hi(u32 packed) { return __uint_as_float(packed & 0xFFFF0000u); }

// ---------- radix-style CSR construction (no global atomics) ----------

__global__ __launch_bounds__(256) void hist_kernel(const int* __restrict__ dst,
    int* __restrict__ counts, int E, int nbuk) {
  __shared__ int h[MAXBUK];
  int tid = threadIdx.x, b = blockIdx.x;
  for (int i = tid; i < nbuk; i += 256) h[i] = 0;
  __syncthreads();
  int ech = (E + NBLK - 1) / NBLK;
  int e0 = b * ech, e1 = min(E, e0 + ech);
  for (int e = e0 + tid; e < e1; e += 256)
    atomicAdd(&h[dst[e] >> BSH], 1);
  __syncthreads();
  for (int i = tid; i < nbuk; i += 256) counts[(size_t)i * NBLK + b] = h[i];
}

__global__ __launch_bounds__(256) void col_scan(int* __restrict__ counts,
    int* __restrict__ colsum, int nbuk) {
  __shared__ int sm[256];
  __shared__ int carry;
  int buk = blockIdx.x, t = threadIdx.x;
  if (t == 0) carry = 0;
  __syncthreads();
  int* row = counts + (size_t)buk * NBLK;
  for (int base = 0; base < NBLK; base += 256) {
    int v = row[base + t];
    sm[t] = v;
    __syncthreads();
    for (int d = 1; d < 256; d <<= 1) {
      int a = (t >= d) ? sm[t - d] : 0;
      __syncthreads();
      sm[t] += a;
      __syncthreads();
    }
    int excl = sm[t] - v + carry;
    row[base + t] = excl;
    __syncthreads();
    if (t == 255) carry = excl + v;
    __syncthreads();
  }
  if (t == 0) colsum[buk] = carry;
}

__global__ __launch_bounds__(256) void scan_block(int* partial, int* total_out, int nb, int n) {
  __shared__ int sm[256];
  __shared__ int carry;
  int t = threadIdx.x;
  if (t == 0) carry = 0;
  __syncthreads();
  for (int base = 0; base < nb; base += 256) {
    int g = base + t;
    int v = (g < nb) ? partial[g] : 0;
    sm[t] = v;
    __syncthreads();
    for (int d = 1; d < 256; d <<= 1) {
      int add = (t >= d) ? sm[t - d] : 0;
      __syncthreads();
      sm[t] += add;
      __syncthreads();
    }
    int excl = sm[t] - v + carry;
    if (g < nb) partial[g] = excl;
    __syncthreads();
    if (t == 255) carry = excl + v;
    __syncthreads();
  }
  if (t == 0) total_out[n] = carry;
}

__global__ __launch_bounds__(256) void scatter_kernel(const int* __restrict__ src,
    const int* __restrict__ dst, const int* __restrict__ counts,
    const int* __restrict__ bb, u32* __restrict__ ebuf, int E, int nbuk) {
  __shared__ int cur[MAXBUK];
  int tid = threadIdx.x, b = blockIdx.x;
  for (int i = tid; i < nbuk; i += 256)
    cur[i] = bb[i] + counts[(size_t)i * NBLK + b];
  __syncthreads();
  int ech = (E + NBLK - 1) / NBLK;
  int e0 = b * ech, e1 = min(E, e0 + ech);
  for (int e = e0 + tid; e < e1; e += 256) {
    int d = dst[e];
    int r = atomicAdd(&cur[d >> BSH], 1);
    ebuf[r] = (u32)src[e] | ((u32)(d & (BNODES - 1)) << 16);   // N < 65536
  }
}

// counts per-node edges in bucket + emits per-bucket total (reduce_chunks folded in)
__global__ __launch_bounds__(256) void bucket_node_count(const u32* __restrict__ ebuf,
    const int* __restrict__ bb, int* __restrict__ cnt, int* __restrict__ bpartial, int N) {
  __shared__ int c[BNODES];
  int b = blockIdx.x, tid = threadIdx.x;
  if (tid < BNODES) c[tid] = 0;
  __syncthreads();
  int e0 = bb[b], e1 = bb[b + 1];
  for (int e = e0 + tid; e < e1; e += 256)
    atomicAdd(&c[ebuf[e] >> 16], 1);
  __syncthreads();
  int node = b * BNODES + tid;
  if (tid < BNODES && node < N) cnt[node] = c[tid];
  if (tid < 64) {
    int s = c[tid] + c[tid + 64];
    #pragma unroll
    for (int o = 32; o > 0; o >>= 1) s += __shfl_down(s, o, 64);
    if (tid == 0) bpartial[b] = s;
  }
}

// chunkoff is the scanned 128-node bucket partials -> index blockIdx.x*2
__global__ __launch_bounds__(256) void scan_chunks(const int* __restrict__ cnt,
    const int* __restrict__ chunkoff, int* __restrict__ rowptr,
    float* __restrict__ dinv, int n) {
  __shared__ int sm[256];
  int t = threadIdx.x, g = blockIdx.x * 256 + t;
  int v = (g < n) ? cnt[g] : 0;
  sm[t] = v;
  __syncthreads();
  for (int d = 1; d < 256; d <<= 1) {
    int add = (t >= d) ? sm[t - d] : 0;
    __syncthreads();
    sm[t] += add;
    __syncthreads();
  }
  if (g < n) {
    rowptr[g] = sm[t] - v + chunkoff[blockIdx.x * 2];
    dinv[g] = rsqrtf((float)(v + 1));       // +1 self-loop
  }
}

__global__ __launch_bounds__(256) void bucket_fill(const u32* __restrict__ ebuf,
    const int* __restrict__ bb, const int* __restrict__ rowptr, u16* __restrict__ csr) {
  __shared__ int c[BNODES];
  int b = blockIdx.x, tid = threadIdx.x;
  if (tid < BNODES) c[tid] = 0;
  __syncthreads();
  int e0 = bb[b], e1 = bb[b + 1];
  for (int e = e0 + tid; e < e1; e += 256) {
    u32 p = ebuf[e];
    int nl = p >> 16;
    int r = atomicAdd(&c[nl], 1);
    csr[rowptr[b * BNODES + nl] + r] = (u16)(p & 0xFFFFu);
  }
}

// ---------- W1 -> bf16 transposed; W2 -> bf16 k-pair-packed [64][64] u32 ----------

__global__ __launch_bounds__(256) void w_prep(const float* __restrict__ W1,
    const float* __restrict__ W2, u16* __restrict__ w1t, u32* __restrict__ w2p) {
  int t = blockIdx.x * 256 + threadIdx.x;     // 36864 threads
  if (t < DH * DIN) {
    int n = t >> 8, k = t & 255;
    w1t[t] = f2bf(W1[k * DH + n]);            // w1t[n*256+k]
  } else {
    int t2 = t - DH * DIN;                    // 0..4095
    int kk = t2 >> 6, j = t2 & 63;
    u32 lo = f2bf(W2[(2 * kk) * DOUT + j]);
    u32 hi = f2bf(W2[(2 * kk + 1) * DOUT + j]);
    w2p[t2] = lo | (hi << 16);                // w2p[kk*64+j] = {W2[2kk][j], W2[2kk+1][j]}
  }
}

// ---------- GEMM1: bf16 MFMA, BM=64 BN=128 BK=64, epilogue dinv*bf16 ----------

__global__ __launch_bounds__(256) void gemm1_mfma(const float* __restrict__ x,
    const u16* __restrict__ w1t, const float* __restrict__ dinv,
    u16* __restrict__ h1, int M) {
  __shared__ u16 As[64][72];
  __shared__ u16 Bs[128][72];
  const int tid = threadIdx.x;
  const int lane = tid & 63, w = tid >> 6;
  const int row16 = lane & 15, quad = lane >> 4;
  const int rowBase = blockIdx.x * 64;
  f32x4 acc[8];
  #pragma unroll
  for (int nt = 0; nt < 8; ++nt) acc[nt] = (f32x4)(0.f);

  for (int kt = 0; kt < DIN; kt += 64) {
    {
      int r = tid >> 2, kq = tid & 3;
      int grow = rowBase + r;
      #pragma unroll
      for (int i = 0; i < 4; ++i) {
        float4 v = make_float4(0.f, 0.f, 0.f, 0.f);
        if (grow < M) v = *(const float4*)&x[(size_t)grow * DIN + kt + kq * 16 + i * 4];
        u32 lo = (u32)f2bf(v.x) | ((u32)f2bf(v.y) << 16);
        u32 hi = (u32)f2bf(v.z) | ((u32)f2bf(v.w) << 16);
        *(uint2*)&As[r][kq * 16 + i * 4] = make_uint2(lo, hi);
      }
    }
    {
      int n = tid >> 1, half = tid & 1;
      const uint4* s = (const uint4*)&w1t[n * DIN + kt + half * 32];
      uint4* d = (uint4*)&Bs[n][half * 32];
      d[0] = s[0]; d[1] = s[1]; d[2] = s[2]; d[3] = s[3];
    }
    __syncthreads();
    #pragma unroll
    for (int ks = 0; ks < 64; ks += 32) {
      bf16x8 a = *(bf16x8*)&As[w * 16 + row16][ks + quad * 8];
      #pragma unroll
      for (int nt = 0; nt < 8; ++nt) {
        bf16x8 b = *(bf16x8*)&Bs[nt * 16 + row16][ks + quad * 8];
        acc[nt] = __builtin_amdgcn_mfma_f32_16x16x32_bf16(a, b, acc[nt], 0, 0, 0);
      }
    }
    __syncthreads();
  }
  #pragma unroll
  for (int reg = 0; reg < 4; ++reg) {
    int row = rowBase + w * 16 + quad * 4 + reg;
    if (row < M) {
      float s = dinv[row];
      #pragma unroll
      for (int nt = 0; nt < 8; ++nt)
        h1[(size_t)row * DH + nt * 16 + row16] = f2bf(acc[nt][reg] * s);
    }
  }
}

// ---------- aggregate1 fused with layer-2 dense transform ----------
// Round-1 gather structure (measured best: 46.9us, occ 66%). After the
// butterfly reduce every lane holds the full aggregated row; epilogue does
// g1 = relu(agg*di + b1) (kept fp32, never materialized), then the 128->64
// matvec with LDS-staged W2 and writes h2 = (g1 @ W2) * di in bf16.
// Deletes: gemm2 kernel, g1 write (12.8MB), g1 read (12.8MB).

__global__ __launch_bounds__(256) void aggregate1_fused(const u16* __restrict__ h,
    const int* __restrict__ rowptr, const u16* __restrict__ csr,
    const float* __restrict__ dinv, const float* __restrict__ bias,
    const u32* __restrict__ w2p, u16* __restrict__ h2, int n) {
  __shared__ u32 w2s[64 * 64];        // 16KB, k-pair packed: w2s[kk*64+j]
  __shared__ float rowbuf[4][128];    // per-wave g1 row exchange
  const int tid = threadIdx.x;
  {   // stage W2 (all threads, before any exit)
    const uint4* s = (const uint4*)w2p;
    uint4* d = (uint4*)w2s;
    #pragma unroll
    for (int i = 0; i < 4; ++i) d[i * 256 + tid] = s[i * 256 + tid];
  }
  __syncthreads();

  const int lane = tid & 63;
  const int wv = tid >> 6;
  const int sub = lane >> 4;          // edge slot within quartet (0..3)
  const int l16 = lane & 15;          // 16B chunk within 256B row
  int node = blockIdx.x * 4 + wv;
  if (node >= n) return;
  node = __builtin_amdgcn_readfirstlane(node);
  const float di = dinv[node];
  const size_t coff = (size_t)l16 * 8;

  float a[8];
  {   // self-loop row (only sub==0 keeps it)
    uint4 v = *(const uint4*)&h[(size_t)node * DH + coff];
    float ms = (sub == 0) ? 1.f : 0.f;
    a[0] = ms * bf2f_lo(v.x); a[1] = ms * bf2f_hi(v.x);
    a[2] = ms * bf2f_lo(v.y); a[3] = ms * bf2f_hi(v.y);
    a[4] = ms * bf2f_lo(v.z); a[5] = ms * bf2f_hi(v.z);
    a[6] = ms * bf2f_lo(v.w); a[7] = ms * bf2f_hi(v.w);
  }

  int p = rowptr[node];
  const int pe = rowptr[node + 1];
  while (p < pe) {
    int g = p + lane;
    int si = (g < pe) ? (int)csr[g] : 0;     // 64 indices, one instruction
    int rem = pe - p; if (rem > 64) rem = 64;
    int t = 0;
    for (; t + 16 <= rem; t += 16) {         // 4 x 1KB gathers in flight
      #pragma unroll
      for (int q = 0; q < 4; ++q) {
        int idx = __shfl(si, t + q * 4 + sub, 64);
        uint4 v = *(const uint4*)&h[(size_t)idx * DH + coff];
        a[0] += bf2f_lo(v.x); a[1] += bf2f_hi(v.x);
        a[2] += bf2f_lo(v.y); a[3] += bf2f_hi(v.y);
        a[4] += bf2f_lo(v.z); a[5] += bf2f_hi(v.z);
        a[6] += bf2f_lo(v.w); a[7] += bf2f_hi(v.w);
      }
    }
    for (; t < rem; t += 4) {                // masked remainder (1-15 edges)
      int e = t + sub;
      int idx = __shfl(si, e & 63, 64);
      uint4 v = *(const uint4*)&h[(size_t)idx * DH + coff];
      float m = (e < rem) ? 1.f : 0.f;
      a[0] = fmaf(m, bf2f_lo(v.x), a[0]); a[1] = fmaf(m, bf2f_hi(v.x), a[1]);
      a[2] = fmaf(m, bf2f_lo(v.y), a[2]); a[3] = fmaf(m, bf2f_hi(v.y), a[3]);
      a[4] = fmaf(m, bf2f_lo(v.z), a[4]); a[5] = fmaf(m, bf2f_hi(v.z), a[5]);
      a[6] = fmaf(m, bf2f_lo(v.w), a[6]); a[7] = fmaf(m, bf2f_hi(v.w), a[7]);
    }
    p += 64;
  }

  #pragma unroll
  for (int i = 0; i < 8; ++i) {              // butterfly: every lane gets full sum
    a[i] += __shfl_xor(a[i], 16, 64);
    a[i] += __shfl_xor(a[i], 32, 64);
  }

  // g1 = relu(a*di + b1)  (fp32, all lanes compute; sub==0 lanes publish)
  const int c0 = l16 * 8;
  float4 b0 = *(const float4*)&bias[c0];
  float4 b1v = *(const float4*)&bias[c0 + 4];
  float f0 = fmaxf(fmaf(a[0], di, b0.x), 0.f);
  float f1 = fmaxf(fmaf(a[1], di, b0.y), 0.f);
  float f2 = fmaxf(fmaf(a[2], di, b0.z), 0.f);
  float f3 = fmaxf(fmaf(a[3], di, b0.w), 0.f);
  float f4 = fmaxf(fmaf(a[4], di, b1v.x), 0.f);
  float f5 = fmaxf(fmaf(a[5], di, b1v.y), 0.f);
  float f6 = fmaxf(fmaf(a[6], di, b1v.z), 0.f);
  float f7 = fmaxf(fmaf(a[7], di, b1v.w), 0.f);
  if (sub == 0) {
    float* rb = &rowbuf[wv][c0];
    rb[0] = f0; rb[1] = f1; rb[2] = f2; rb[3] = f3;
    rb[4] = f4; rb[5] = f5; rb[6] = f6; rb[7] = f7;
  }
  // wave-internal LDS write->read: DS pipe is in-order per wave; fence for safety
  asm volatile("s_waitcnt lgkmcnt(0)" ::: "memory");
  __builtin_amdgcn_sched_barrier(0);

  // matvec: out[lane] = sum_k g1[k] * W2[k][lane]
  const float* rb = rowbuf[wv];
  const u32* wrow = &w2s[lane];
  float o = 0.f;
  #pragma unroll
  for (int kk = 0; kk < 64; kk += 4) {
    float4 r01 = *(const float4*)&rb[2 * kk];      // broadcast reads
    float4 r23 = *(const float4*)&rb[2 * kk + 4];
    u32 w0 = wrow[(kk + 0) * 64];
    u32 w1 = wrow[(kk + 1) * 64];
    u32 w2v = wrow[(kk + 2) * 64];
    u32 w3 = wrow[(kk + 3) * 64];
    o = fmaf(r01.x, bf2f_lo(w0), o); o = fmaf(r01.y, bf2f_hi(w0), o);
    o = fmaf(r01.z, bf2f_lo(w1), o); o = fmaf(r01.w, bf2f_hi(w1), o);
    o = fmaf(r23.x, bf2f_lo(w2v), o); o = fmaf(r23.y, bf2f_hi(w2v), o);
    o = fmaf(r23.z, bf2f_lo(w3), o); o = fmaf(r23.w, bf2f_hi(w3), o);
  }
  o *= di;                                   // layer-2 pre-scale (was gemm2 epilogue)
  h2[(size_t)node * DOUT + lane] = f2bf(o);
}

// ---------- aggregate2: Round-1 form (8 edge-groups x 8 lanes), u16 csr ----------

__global__ __launch_bounds__(256) void aggregate2(const u16* __restrict__ h,
    const int* __restrict__ rowptr, const u16* __restrict__ csr,
    const float* __restrict__ dinv, const float* __restrict__ bias,
    float* __restrict__ out, int n) {
  const int lane = threadIdx.x & 63;
  const int sub = lane >> 3;          // edge slot within octet (0..7)
  const int l8 = lane & 7;            // 16B chunk within 128B row
  int node = blockIdx.x * 4 + (threadIdx.x >> 6);
  if (node >= n) return;
  node = __builtin_amdgcn_readfirstlane(node);
  const float di = dinv[node];
  const size_t coff = (size_t)l8 * 8;

  float a[8];
  {
    uint4 v = *(const uint4*)&h[(size_t)node * DOUT + coff];
    float ms = (sub == 0) ? 1.f : 0.f;
    a[0] = ms * bf2f_lo(v.x); a[1] = ms * bf2f_hi(v.x);
    a[2] = ms * bf2f_lo(v.y); a[3] = ms * bf2f_hi(v.y);
    a[4] = ms * bf2f_lo(v.z); a[5] = ms * bf2f_hi(v.z);
    a[6] = ms * bf2f_lo(v.w); a[7] = ms * bf2f_hi(v.w);
  }

  int p = rowptr[node];
  const int pe = rowptr[node + 1];
  while (p < pe) {
    int g = p + lane;
    int si = (g < pe) ? (int)csr[g] : 0;
    int rem = pe - p; if (rem > 64) rem = 64;
    int t = 0;
    for (; t + 32 <= rem; t += 32) {         // 4 x 1KB gathers in flight
      #pragma unroll
      for (int q = 0; q < 4; ++q) {
        int idx = __shfl(si, t + q * 8 + sub, 64);
        uint4 v = *(const uint4*)&h[(size_t)idx * DOUT + coff];
        a[0] += bf2f_lo(v.x); a[1] += bf2f_hi(v.x);
        a[2] += bf2f_lo(v.y); a[3] += bf2f_hi(v.y);
        a[4] += bf2f_lo(v.z); a[5] += bf2f_hi(v.z);
        a[6] += bf2f_lo(v.w); a[7] += bf2f_hi(v.w);
      }
    }
    for (; t < rem; t += 8) {                // masked remainder (1-31 edges)
      int e = t + sub;
      int idx = __shfl(si, e & 63, 64);
      uint4 v = *(const uint4*)&h[(size_t)idx * DOUT + coff];
      float m = (e < rem) ? 1.f : 0.f;
      a[0] = fmaf(m, bf2f_lo(v.x), a[0]); a[1] = fmaf(m, bf2f_hi(v.x), a[1]);
      a[2] = fmaf(m, bf2f_lo(v.y), a[2]); a[3] = fmaf(m, bf2f_hi(v.y), a[3]);
      a[4] = fmaf(m, bf2f_lo(v.z), a[4]); a[5] = fmaf(m, bf2f_hi(v.z), a[5]);
      a[6] = fmaf(m, bf2f_lo(v.w), a[6]); a[7] = fmaf(m, bf2f_hi(v.w), a[7]);
    }
    p += 64;
  }

  #pragma unroll
  for (int i = 0; i < 8; ++i) {              // reduce across the 8 edge-groups
    a[i] += __shfl_xor(a[i], 8, 64);
    a[i] += __shfl_xor(a[i], 16, 64);
    a[i] += __shfl_xor(a[i], 32, 64);
  }

  if (sub == 0) {                            // lanes 0..7 hold the full row
    const int c0 = l8 * 8;
    float4 b0 = *(const float4*)&bias[c0];
    float4 b1 = *(const float4*)&bias[c0 + 4];
    float4 r0, r1;
    r0.x = fmaf(a[0], di, b0.x);
    r0.y = fmaf(a[1], di, b0.y);
    r0.z = fmaf(a[2], di, b0.z);
    r0.w = fmaf(a[3], di, b0.w);
    r1.x = fmaf(a[4], di, b1.x);
    r1.y = fmaf(a[5], di, b1.y);
    r1.z = fmaf(a[6], di, b1.z);
    r1.w = fmaf(a[7], di, b1.w);
    *(float4*)&out[(size_t)node * DOUT + c0] = r0;
    *(float4*)&out[(size_t)node * DOUT + c0 + 4] = r1;
  }
}

// ---------- launch ----------

extern "C" void kernel_launch(void* const* d_in, const int* in_sizes, int n_in,
                              void* d_out, int out_size, void* d_ws, size_t ws_size,
                              hipStream_t stream) {
  const float* x  = (const float*)d_in[0];
  const int*   ei = (const int*)d_in[1];
  const float* W1 = (const float*)d_in[2];
  const float* b1 = (const float*)d_in[3];
  const float* W2 = (const float*)d_in[4];
  const float* b2 = (const float*)d_in[5];
  float* out = (float*)d_out;

  const int N = in_sizes[0] / DIN;   // 50000
  const int E = in_sizes[1] / 2;     // 1600000
  const int* src = ei;
  const int* dst = ei + E;
  const int NB = (N + 255) / 256;
  const int nbuk = (N + BNODES - 1) / BNODES;   // 391 (<= MAXBUK)

  char* ws = (char*)d_ws;
  size_t o = 0;
  auto alloc = [&](size_t bytes) { size_t r = o; o += (bytes + 511) & ~(size_t)511; return r; };
  size_t colsum_o  = alloc((size_t)(nbuk + 1) * 4);
  size_t counts_o  = alloc((size_t)nbuk * NBLK * 4);
  size_t rowptr_o  = alloc((size_t)(N + 1) * 4);
  size_t partial_o = alloc((size_t)(nbuk + 1) * 4);
  size_t dinv_o    = alloc((size_t)N * 4);
  size_t cnt_o     = alloc((size_t)N * 4);
  size_t w1t_o     = alloc((size_t)DH * DIN * 2);
  size_t w2p_o     = alloc((size_t)(DH / 2) * DOUT * 4);
  size_t csr_o     = alloc((size_t)E * 2);        // u16 indices
  size_t h1_o      = alloc((size_t)N * DH * 2);   // bf16
  size_t big_o     = alloc((size_t)E * 4);        // ebuf, later h2
  size_t h2_o      = big_o;   // ebuf dead after bucket_fill -> h2 (bf16, 6.4MB)

  int*   colsum  = (int*)(ws + colsum_o);   // becomes bb after scan_block
  int*   counts  = (int*)(ws + counts_o);
  int*   rowptr  = (int*)(ws + rowptr_o);
  int*   partial = (int*)(ws + partial_o);
  float* dinv    = (float*)(ws + dinv_o);
  int*   cnt     = (int*)(ws + cnt_o);
  u16*   w1t     = (u16*)(ws + w1t_o);
  u32*   w2p     = (u32*)(ws + w2p_o);
  u16*   csr     = (u16*)(ws + csr_o);
  u16*   h1      = (u16*)(ws + h1_o);
  u32*   ebuf    = (u32*)(ws + big_o);
  u16*   h2      = (u16*)(ws + h2_o);

  w_prep<<<(DH * DIN + (DH / 2) * DOUT) / 256, 256, 0, stream>>>(W1, W2, w1t, w2p);
  hist_kernel<<<NBLK, 256, 0, stream>>>(dst, counts, E, nbuk);
  col_scan<<<nbuk, 256, 0, stream>>>(counts, colsum, nbuk);
  scan_block<<<1, 256, 0, stream>>>(colsum, colsum, nbuk, nbuk);  // colsum -> bb, bb[nbuk]=E
  scatter_kernel<<<NBLK, 256, 0, stream>>>(src, dst, counts, colsum, ebuf, E, nbuk);
  bucket_node_count<<<nbuk, 256, 0, stream>>>(ebuf, colsum, cnt, partial, N);
  scan_block<<<1, 256, 0, stream>>>(partial, rowptr, nbuk, N);    // partial -> scanned, rowptr[N]=E
  scan_chunks<<<NB, 256, 0, stream>>>(cnt, partial, rowptr, dinv, N);
  bucket_fill<<<nbuk, 256, 0, stream>>>(ebuf, colsum, rowptr, csr);

  gemm1_mfma<<<(N + 63) / 64, 256, 0, stream>>>(x, w1t, dinv, h1, N);
  aggregate1_fused<<<(N + 3) / 4, 256, 0, stream>>>(h1, rowptr, csr, dinv, b1, w2p, h2, N);
  aggregate2<<<(N + 3) / 4, 256, 0, stream>>>(h2, rowptr, csr, dinv, b2, out, N);
}

// Round 5
// 239.977 us; speedup vs baseline: 1.0306x; 1.0071x over previous
//
#include <hip/hip_runtime.h>

#define DIN 256
#define DH  128
#define DOUT 64
#define BSH  7          // bucket = 128 nodes
#define BNODES 128
#define MAXBUK 400      // >= ceil(N/128); N=50000 -> 391
#define NBLK 512        // histogram/scatter grid

typedef unsigned int  u32;
typedef unsigned short u16;
typedef __attribute__((ext_vector_type(8))) short bf16x8;
typedef __attribute__((ext_vector_type(4))) float f32x4;

__device__ inline u16 f2bf(float f) {            // fp32 -> bf16 round-nearest-even
  u32 u = __float_as_uint(f);
  u32 r = u + 0x7FFF + ((u >> 16) & 1);
  return (u16)(r >> 16);
}
__device__ inline float bf2f_lo(u32 packed) { return __uint_as_float(packed << 16); }
__device__ inline float bf2f_hi(u32 packed) { return __uint_as_float(packed & 0xFFFF0000u); }

// ---------- radix-style CSR construction (no global atomics) ----------

__global__ __launch_bounds__(256) void hist_kernel(const int* __restrict__ dst,
    int* __restrict__ counts, int E, int nbuk) {
  __shared__ int h[MAXBUK];
  int tid = threadIdx.x, b = blockIdx.x;
  for (int i = tid; i < nbuk; i += 256) h[i] = 0;
  __syncthreads();
  int ech = (E + NBLK - 1) / NBLK;
  int e0 = b * ech, e1 = min(E, e0 + ech);
  for (int e = e0 + tid; e < e1; e += 256)
    atomicAdd(&h[dst[e] >> BSH], 1);
  __syncthreads();
  for (int i = tid; i < nbuk; i += 256) counts[(size_t)i * NBLK + b] = h[i];
}

__global__ __launch_bounds__(256) void col_scan(int* __restrict__ counts,
    int* __restrict__ colsum, int nbuk) {
  __shared__ int sm[256];
  __shared__ int carry;
  int buk = blockIdx.x, t = threadIdx.x;
  if (t == 0) carry = 0;
  __syncthreads();
  int* row = counts + (size_t)buk * NBLK;
  for (int base = 0; base < NBLK; base += 256) {
    int v = row[base + t];
    sm[t] = v;
    __syncthreads();
    for (int d = 1; d < 256; d <<= 1) {
      int a = (t >= d) ? sm[t - d] : 0;
      __syncthreads();
      sm[t] += a;
      __syncthreads();
    }
    int excl = sm[t] - v + carry;
    row[base + t] = excl;
    __syncthreads();
    if (t == 255) carry = excl + v;
    __syncthreads();
  }
  if (t == 0) colsum[buk] = carry;
}

__global__ __launch_bounds__(256) void scan_block(int* partial, int* total_out, int nb, int n) {
  __shared__ int sm[256];
  __shared__ int carry;
  int t = threadIdx.x;
  if (t == 0) carry = 0;
  __syncthreads();
  for (int base = 0; base < nb; base += 256) {
    int g = base + t;
    int v = (g < nb) ? partial[g] : 0;
    sm[t] = v;
    __syncthreads();
    for (int d = 1; d < 256; d <<= 1) {
      int add = (t >= d) ? sm[t - d] : 0;
      __syncthreads();
      sm[t] += add;
      __syncthreads();
    }
    int excl = sm[t] - v + carry;
    if (g < nb) partial[g] = excl;
    __syncthreads();
    if (t == 255) carry = excl + v;
    __syncthreads();
  }
  if (t == 0) total_out[n] = carry;
}

__global__ __launch_bounds__(256) void scatter_kernel(const int* __restrict__ src,
    const int* __restrict__ dst, const int* __restrict__ counts,
    const int* __restrict__ bb, u32* __restrict__ ebuf, int E, int nbuk) {
  __shared__ int cur[MAXBUK];
  int tid = threadIdx.x, b = blockIdx.x;
  for (int i = tid; i < nbuk; i += 256)
    cur[i] = bb[i] + counts[(size_t)i * NBLK + b];
  __syncthreads();
  int ech = (E + NBLK - 1) / NBLK;
  int e0 = b * ech, e1 = min(E, e0 + ech);
  for (int e = e0 + tid; e < e1; e += 256) {
    int d = dst[e];
    int r = atomicAdd(&cur[d >> BSH], 1);
    ebuf[r] = (u32)src[e] | ((u32)(d & (BNODES - 1)) << 16);   // N < 65536
  }
}

// counts per-node edges in bucket + emits per-bucket total (reduce_chunks folded in)
__global__ __launch_bounds__(256) void bucket_node_count(const u32* __restrict__ ebuf,
    const int* __restrict__ bb, int* __restrict__ cnt, int* __restrict__ bpartial, int N) {
  __shared__ int c[BNODES];
  int b = blockIdx.x, tid = threadIdx.x;
  if (tid < BNODES) c[tid] = 0;
  __syncthreads();
  int e0 = bb[b], e1 = bb[b + 1];
  for (int e = e0 + tid; e < e1; e += 256)
    atomicAdd(&c[ebuf[e] >> 16], 1);
  __syncthreads();
  int node = b * BNODES + tid;
  if (tid < BNODES && node < N) cnt[node] = c[tid];
  if (tid < 64) {
    int s = c[tid] + c[tid + 64];
    #pragma unroll
    for (int o = 32; o > 0; o >>= 1) s += __shfl_down(s, o, 64);
    if (tid == 0) bpartial[b] = s;
  }
}

// chunkoff is the scanned 128-node bucket partials -> index blockIdx.x*2
__global__ __launch_bounds__(256) void scan_chunks(const int* __restrict__ cnt,
    const int* __restrict__ chunkoff, int* __restrict__ rowptr,
    float* __restrict__ dinv, int n) {
  __shared__ int sm[256];
  int t = threadIdx.x, g = blockIdx.x * 256 + t;
  int v = (g < n) ? cnt[g] : 0;
  sm[t] = v;
  __syncthreads();
  for (int d = 1; d < 256; d <<= 1) {
    int add = (t >= d) ? sm[t - d] : 0;
    __syncthreads();
    sm[t] += add;
    __syncthreads();
  }
  if (g < n) {
    rowptr[g] = sm[t] - v + chunkoff[blockIdx.x * 2];
    dinv[g] = rsqrtf((float)(v + 1));       // +1 self-loop
  }
}

__global__ __launch_bounds__(256) void bucket_fill(const u32* __restrict__ ebuf,
    const int* __restrict__ bb, const int* __restrict__ rowptr, u16* __restrict__ csr) {
  __shared__ int c[BNODES];
  int b = blockIdx.x, tid = threadIdx.x;
  if (tid < BNODES) c[tid] = 0;
  __syncthreads();
  int e0 = bb[b], e1 = bb[b + 1];
  for (int e = e0 + tid; e < e1; e += 256) {
    u32 p = ebuf[e];
    int nl = p >> 16;
    int r = atomicAdd(&c[nl], 1);
    csr[rowptr[b * BNODES + nl] + r] = (u16)(p & 0xFFFFu);
  }
}

// ---------- W1 -> bf16 transposed; W2 -> bf16 transposed [64][128] ----------

__global__ __launch_bounds__(256) void w_prep(const float* __restrict__ W1,
    const float* __restrict__ W2, u16* __restrict__ w1t, u16* __restrict__ w2t) {
  int t = blockIdx.x * 256 + threadIdx.x;     // 40960 threads
  if (t < DH * DIN) {
    int n = t >> 8, k = t & 255;
    w1t[t] = f2bf(W1[k * DH + n]);            // w1t[n*256+k]
  } else {
    int t2 = t - DH * DIN;                    // 0..8191
    int j = t2 >> 7, k = t2 & 127;
    w2t[t2] = f2bf(W2[k * DOUT + j]);         // w2t[j*128+k]  (W2^T, bf16)
  }
}

// ---------- GEMM1: bf16 MFMA, BM=64 BN=128 BK=64, epilogue dinv*bf16 ----------

__global__ __launch_bounds__(256) void gemm1_mfma(const float* __restrict__ x,
    const u16* __restrict__ w1t, const float* __restrict__ dinv,
    u16* __restrict__ h1, int M) {
  __shared__ u16 As[64][72];
  __shared__ u16 Bs[128][72];
  const int tid = threadIdx.x;
  const int lane = tid & 63, w = tid >> 6;
  const int row16 = lane & 15, quad = lane >> 4;
  const int rowBase = blockIdx.x * 64;
  f32x4 acc[8];
  #pragma unroll
  for (int nt = 0; nt < 8; ++nt) acc[nt] = (f32x4)(0.f);

  for (int kt = 0; kt < DIN; kt += 64) {
    {
      int r = tid >> 2, kq = tid & 3;
      int grow = rowBase + r;
      #pragma unroll
      for (int i = 0; i < 4; ++i) {
        float4 v = make_float4(0.f, 0.f, 0.f, 0.f);
        if (grow < M) v = *(const float4*)&x[(size_t)grow * DIN + kt + kq * 16 + i * 4];
        u32 lo = (u32)f2bf(v.x) | ((u32)f2bf(v.y) << 16);
        u32 hi = (u32)f2bf(v.z) | ((u32)f2bf(v.w) << 16);
        *(uint2*)&As[r][kq * 16 + i * 4] = make_uint2(lo, hi);
      }
    }
    {
      int n = tid >> 1, half = tid & 1;
      const uint4* s = (const uint4*)&w1t[n * DIN + kt + half * 32];
      uint4* d = (uint4*)&Bs[n][half * 32];
      d[0] = s[0]; d[1] = s[1]; d[2] = s[2]; d[3] = s[3];
    }
    __syncthreads();
    #pragma unroll
    for (int ks = 0; ks < 64; ks += 32) {
      bf16x8 a = *(bf16x8*)&As[w * 16 + row16][ks + quad * 8];
      #pragma unroll
      for (int nt = 0; nt < 8; ++nt) {
        bf16x8 b = *(bf16x8*)&Bs[nt * 16 + row16][ks + quad * 8];
        acc[nt] = __builtin_amdgcn_mfma_f32_16x16x32_bf16(a, b, acc[nt], 0, 0, 0);
      }
    }
    __syncthreads();
  }
  #pragma unroll
  for (int reg = 0; reg < 4; ++reg) {
    int row = rowBase + w * 16 + quad * 4 + reg;
    if (row < M) {
      float s = dinv[row];
      #pragma unroll
      for (int nt = 0; nt < 8; ++nt)
        h1[(size_t)row * DH + nt * 16 + row16] = f2bf(acc[nt][reg] * s);
    }
  }
}

// ---------- aggregate1 fused with layer-2 transform via MFMA ----------
// Gather structure unchanged (R1 measured best). Epilogue: relu'd row stored
// to LDS as bf16; after one barrier the block's 4 rows (padded to 16) are
// multiplied by LDS-staged W2^T with 4 MFMAs per wave (wave = 16-col N-tile).
// Replaces the 350-VALU-op/node per-lane matvec (the +14us of R4).
// Rows padded to 136 u16 (272B) -> fragment reads are 2-way bank aliased (free).

__global__ __launch_bounds__(256) void aggregate1_fused(const u16* __restrict__ h,
    const int* __restrict__ rowptr, const u16* __restrict__ csr,
    const float* __restrict__ dinv, const float* __restrict__ bias,
    const u16* __restrict__ w2t, u16* __restrict__ h2, int n) {
  __shared__ __align__(16) u16 w2s[64 * 136];     // W2^T [64 cols][128 k], padded rows
  __shared__ __align__(16) u16 rowbuf[16 * 136];  // 16 M-rows (4 real), padded
  const int tid = threadIdx.x;
  const int lane = tid & 63;
  const int wv = tid >> 6;
  const int row16 = lane & 15, quad = lane >> 4;

  {   // stage W2^T: 64 rows x 16 uint4, row-padded
    #pragma unroll
    for (int i = 0; i < 4; ++i) {
      int flat = i * 256 + tid;                  // 0..1023
      int r = flat >> 4, q = flat & 15;
      *(uint4*)&w2s[r * 136 + q * 8] = *(const uint4*)&w2t[r * 128 + q * 8];
    }
  }
  if (wv < 3) {     // zero pad rows 4..15 of rowbuf (waves 0-2, one store/lane)
    int r = 4 + wv * 4 + quad;
    *(uint4*)&rowbuf[r * 136 + row16 * 8] = make_uint4(0, 0, 0, 0);
  }

  const int sub = quad;               // edge slot within quartet (0..3)
  const int l16 = row16;              // 16B chunk within 256B row
  const int nodeBase = blockIdx.x * 4;
  int node = nodeBase + wv;
  const bool active = node < n;
  node = __builtin_amdgcn_readfirstlane(active ? node : (n - 1));
  const float di = dinv[node];
  const size_t coff = (size_t)l16 * 8;

  float a[8];
  {   // self-loop row (only sub==0 keeps it)
    uint4 v = *(const uint4*)&h[(size_t)node * DH + coff];
    float ms = (sub == 0) ? 1.f : 0.f;
    a[0] = ms * bf2f_lo(v.x); a[1] = ms * bf2f_hi(v.x);
    a[2] = ms * bf2f_lo(v.y); a[3] = ms * bf2f_hi(v.y);
    a[4] = ms * bf2f_lo(v.z); a[5] = ms * bf2f_hi(v.z);
    a[6] = ms * bf2f_lo(v.w); a[7] = ms * bf2f_hi(v.w);
  }

  int p = rowptr[node];
  const int pe = active ? rowptr[node + 1] : p;   // inactive wave: empty range
  while (p < pe) {
    int g = p + lane;
    int si = (g < pe) ? (int)csr[g] : 0;     // 64 indices, one instruction
    int rem = pe - p; if (rem > 64) rem = 64;
    int t = 0;
    for (; t + 16 <= rem; t += 16) {         // 4 x 1KB gathers in flight
      #pragma unroll
      for (int q = 0; q < 4; ++q) {
        int idx = __shfl(si, t + q * 4 + sub, 64);
        uint4 v = *(const uint4*)&h[(size_t)idx * DH + coff];
        a[0] += bf2f_lo(v.x); a[1] += bf2f_hi(v.x);
        a[2] += bf2f_lo(v.y); a[3] += bf2f_hi(v.y);
        a[4] += bf2f_lo(v.z); a[5] += bf2f_hi(v.z);
        a[6] += bf2f_lo(v.w); a[7] += bf2f_hi(v.w);
      }
    }
    for (; t < rem; t += 4) {                // masked remainder (1-15 edges)
      int e = t + sub;
      int idx = __shfl(si, e & 63, 64);
      uint4 v = *(const uint4*)&h[(size_t)idx * DH + coff];
      float m = (e < rem) ? 1.f : 0.f;
      a[0] = fmaf(m, bf2f_lo(v.x), a[0]); a[1] = fmaf(m, bf2f_hi(v.x), a[1]);
      a[2] = fmaf(m, bf2f_lo(v.y), a[2]); a[3] = fmaf(m, bf2f_hi(v.y), a[3]);
      a[4] = fmaf(m, bf2f_lo(v.z), a[4]); a[5] = fmaf(m, bf2f_hi(v.z), a[5]);
      a[6] = fmaf(m, bf2f_lo(v.w), a[6]); a[7] = fmaf(m, bf2f_hi(v.w), a[7]);
    }
    p += 64;
  }

  #pragma unroll
  for (int i = 0; i < 8; ++i) {              // butterfly: every lane gets full sum
    a[i] += __shfl_xor(a[i], 16, 64);
    a[i] += __shfl_xor(a[i], 32, 64);
  }

  // g1 = relu(a*di + b1) -> bf16 -> rowbuf row wv (sub==0 lanes, one b128 store)
  if (sub == 0) {
    const int c0 = l16 * 8;
    float4 b0 = *(const float4*)&bias[c0];
    float4 b1v = *(const float4*)&bias[c0 + 4];
    float f0 = fmaxf(fmaf(a[0], di, b0.x), 0.f);
    float f1 = fmaxf(fmaf(a[1], di, b0.y), 0.f);
    float f2 = fmaxf(fmaf(a[2], di, b0.z), 0.f);
    float f3 = fmaxf(fmaf(a[3], di, b0.w), 0.f);
    float f4 = fmaxf(fmaf(a[4], di, b1v.x), 0.f);
    float f5 = fmaxf(fmaf(a[5], di, b1v.y), 0.f);
    float f6 = fmaxf(fmaf(a[6], di, b1v.z), 0.f);
    float f7 = fmaxf(fmaf(a[7], di, b1v.w), 0.f);
    uint4 pk;
    pk.x = (u32)f2bf(f0) | ((u32)f2bf(f1) << 16);
    pk.y = (u32)f2bf(f2) | ((u32)f2bf(f3) << 16);
    pk.z = (u32)f2bf(f4) | ((u32)f2bf(f5) << 16);
    pk.w = (u32)f2bf(f6) | ((u32)f2bf(f7) << 16);
    *(uint4*)&rowbuf[wv * 136 + l16 * 8] = pk;
  }
  __syncthreads();

  // block matmul: [16 x 128](rows 0-3 real) @ W2^T -> each wave owns 16 cols
  f32x4 acc = (f32x4)(0.f);
  #pragma unroll
  for (int kt = 0; kt < 4; ++kt) {
    bf16x8 af = *(bf16x8*)&rowbuf[row16 * 136 + kt * 32 + quad * 8];
    bf16x8 bf = *(bf16x8*)&w2s[(wv * 16 + row16) * 136 + kt * 32 + quad * 8];
    acc = __builtin_amdgcn_mfma_f32_16x16x32_bf16(af, bf, acc, 0, 0, 0);
  }
  // C layout: col = lane&15, row = (lane>>4)*4 + reg; rows 0-3 live in quad==0
  if (quad == 0) {
    #pragma unroll
    for (int reg = 0; reg < 4; ++reg) {
      int nr = nodeBase + reg;
      if (nr < n)
        h2[(size_t)nr * DOUT + wv * 16 + row16] = f2bf(acc[reg] * dinv[nr]);
    }
  }
}

// ---------- aggregate2: 8 edge-groups x 8 lanes, u16 csr ----------

__global__ __launch_bounds__(256) void aggregate2(const u16* __restrict__ h,
    const int* __restrict__ rowptr, const u16* __restrict__ csr,
    const float* __restrict__ dinv, const float* __restrict__ bias,
    float* __restrict__ out, int n) {
  const int lane = threadIdx.x & 63;
  const int sub = lane >> 3;          // edge slot within octet (0..7)
  const int l8 = lane & 7;            // 16B chunk within 128B row
  int node = blockIdx.x * 4 + (threadIdx.x >> 6);
  if (node >= n) return;
  node = __builtin_amdgcn_readfirstlane(node);
  const float di = dinv[node];
  const size_t coff = (size_t)l8 * 8;

  float a[8];
  {
    uint4 v = *(const uint4*)&h[(size_t)node * DOUT + coff];
    float ms = (sub == 0) ? 1.f : 0.f;
    a[0] = ms * bf2f_lo(v.x); a[1] = ms * bf2f_hi(v.x);
    a[2] = ms * bf2f_lo(v.y); a[3] = ms * bf2f_hi(v.y);
    a[4] = ms * bf2f_lo(v.z); a[5] = ms * bf2f_hi(v.z);
    a[6] = ms * bf2f_lo(v.w); a[7] = ms * bf2f_hi(v.w);
  }

  int p = rowptr[node];
  const int pe = rowptr[node + 1];
  while (p < pe) {
    int g = p + lane;
    int si = (g < pe) ? (int)csr[g] : 0;
    int rem = pe - p; if (rem > 64) rem = 64;
    int t = 0;
    for (; t + 32 <= rem; t += 32) {         // 4 x 1KB gathers in flight
      #pragma unroll
      for (int q = 0; q < 4; ++q) {
        int idx = __shfl(si, t + q * 8 + sub, 64);
        uint4 v = *(const uint4*)&h[(size_t)idx * DOUT + coff];
        a[0] += bf2f_lo(v.x); a[1] += bf2f_hi(v.x);
        a[2] += bf2f_lo(v.y); a[3] += bf2f_hi(v.y);
        a[4] += bf2f_lo(v.z); a[5] += bf2f_hi(v.z);
        a[6] += bf2f_lo(v.w); a[7] += bf2f_hi(v.w);
      }
    }
    for (; t < rem; t += 8) {                // masked remainder (1-31 edges)
      int e = t + sub;
      int idx = __shfl(si, e & 63, 64);
      uint4 v = *(const uint4*)&h[(size_t)idx * DOUT + coff];
      float m = (e < rem) ? 1.f : 0.f;
      a[0] = fmaf(m, bf2f_lo(v.x), a[0]); a[1] = fmaf(m, bf2f_hi(v.x), a[1]);
      a[2] = fmaf(m, bf2f_lo(v.y), a[2]); a[3] = fmaf(m, bf2f_hi(v.y), a[3]);
      a[4] = fmaf(m, bf2f_lo(v.z), a[4]); a[5] = fmaf(m, bf2f_hi(v.z), a[5]);
      a[6] = fmaf(m, bf2f_lo(v.w), a[6]); a[7] = fmaf(m, bf2f_hi(v.w), a[7]);
    }
    p += 64;
  }

  #pragma unroll
  for (int i = 0; i < 8; ++i) {              // reduce across the 8 edge-groups
    a[i] += __shfl_xor(a[i], 8, 64);
    a[i] += __shfl_xor(a[i], 16, 64);
    a[i] += __shfl_xor(a[i], 32, 64);
  }

  if (sub == 0) {                            // lanes 0..7 hold the full row
    const int c0 = l8 * 8;
    float4 b0 = *(const float4*)&bias[c0];
    float4 b1 = *(const float4*)&bias[c0 + 4];
    float4 r0, r1;
    r0.x = fmaf(a[0], di, b0.x);
    r0.y = fmaf(a[1], di, b0.y);
    r0.z = fmaf(a[2], di, b0.z);
    r0.w = fmaf(a[3], di, b0.w);
    r1.x = fmaf(a[4], di, b1.x);
    r1.y = fmaf(a[5], di, b1.y);
    r1.z = fmaf(a[6], di, b1.z);
    r1.w = fmaf(a[7], di, b1.w);
    *(float4*)&out[(size_t)node * DOUT + c0] = r0;
    *(float4*)&out[(size_t)node * DOUT + c0 + 4] = r1;
  }
}

// ---------- launch ----------

extern "C" void kernel_launch(void* const* d_in, const int* in_sizes, int n_in,
                              void* d_out, int out_size, void* d_ws, size_t ws_size,
                              hipStream_t stream) {
  const float* x  = (const float*)d_in[0];
  const int*   ei = (const int*)d_in[1];
  const float* W1 = (const float*)d_in[2];
  const float* b1 = (const float*)d_in[3];
  const float* W2 = (const float*)d_in[4];
  const float* b2 = (const float*)d_in[5];
  float* out = (float*)d_out;

  const int N = in_sizes[0] / DIN;   // 50000
  const int E = in_sizes[1] / 2;     // 1600000
  const int* src = ei;
  const int* dst = ei + E;
  const int NB = (N + 255) / 256;
  const int nbuk = (N + BNODES - 1) / BNODES;   // 391 (<= MAXBUK)

  char* ws = (char*)d_ws;
  size_t o = 0;
  auto alloc = [&](size_t bytes) { size_t r = o; o += (bytes + 511) & ~(size_t)511; return r; };
  size_t colsum_o  = alloc((size_t)(nbuk + 1) * 4);
  size_t counts_o  = alloc((size_t)nbuk * NBLK * 4);
  size_t rowptr_o  = alloc((size_t)(N + 1) * 4);
  size_t partial_o = alloc((size_t)(nbuk + 1) * 4);
  size_t dinv_o    = alloc((size_t)N * 4);
  size_t cnt_o     = alloc((size_t)N * 4);
  size_t w1t_o     = alloc((size_t)DH * DIN * 2);
  size_t w2t_o     = alloc((size_t)DOUT * DH * 2);
  size_t csr_o     = alloc((size_t)E * 2);        // u16 indices
  size_t h1_o      = alloc((size_t)N * DH * 2);   // bf16
  size_t big_o     = alloc((size_t)E * 4);        // ebuf, later h2
  size_t h2_o      = big_o;   // ebuf dead after bucket_fill -> h2 (bf16, 6.4MB)

  int*   colsum  = (int*)(ws + colsum_o);   // becomes bb after scan_block
  int*   counts  = (int*)(ws + counts_o);
  int*   rowptr  = (int*)(ws + rowptr_o);
  int*   partial = (int*)(ws + partial_o);
  float* dinv    = (float*)(ws + dinv_o);
  int*   cnt     = (int*)(ws + cnt_o);
  u16*   w1t     = (u16*)(ws + w1t_o);
  u16*   w2t     = (u16*)(ws + w2t_o);
  u16*   csr     = (u16*)(ws + csr_o);
  u16*   h1      = (u16*)(ws + h1_o);
  u32*   ebuf    = (u32*)(ws + big_o);
  u16*   h2      = (u16*)(ws + h2_o);

  w_prep<<<(DH * DIN + DOUT * DH) / 256, 256, 0, stream>>>(W1, W2, w1t, w2t);
  hist_kernel<<<NBLK, 256, 0, stream>>>(dst, counts, E, nbuk);
  col_scan<<<nbuk, 256, 0, stream>>>(counts, colsum, nbuk);
  scan_block<<<1, 256, 0, stream>>>(colsum, colsum, nbuk, nbuk);  // colsum -> bb, bb[nbuk]=E
  scatter_kernel<<<NBLK, 256, 0, stream>>>(src, dst, counts, colsum, ebuf, E, nbuk);
  bucket_node_count<<<nbuk, 256, 0, stream>>>(ebuf, colsum, cnt, partial, N);
  scan_block<<<1, 256, 0, stream>>>(partial, rowptr, nbuk, N);    // partial -> scanned, rowptr[N]=E
  scan_chunks<<<NB, 256, 0, stream>>>(cnt, partial, rowptr, dinv, N);
  bucket_fill<<<nbuk, 256, 0, stream>>>(ebuf, colsum, rowptr, csr);

  gemm1_mfma<<<(N + 63) / 64, 256, 0, stream>>>(x, w1t, dinv, h1, N);
  aggregate1_fused<<<(N + 3) / 4, 256, 0, stream>>>(h1, rowptr, csr, dinv, b1, w2t, h2, N);
  aggregate2<<<(N + 3) / 4, 256, 0, stream>>>(h2, rowptr, csr, dinv, b2, out, N);
}